// Round 1
// baseline (384.627 us; speedup 1.0000x reference)
//
#include <hip/hip_runtime.h>

#define B_N 262144
#define OBS_N 8
#define NF_N 4

__device__ __forceinline__ float rcpf_(float x) { return __builtin_amdgcn_rcpf(x); }
__device__ __forceinline__ float sigm_(float x) { return rcpf_(1.0f + __expf(-x)); }
__device__ __forceinline__ float tanh_(float x) {
    // overflow-safe tanh: 1 exp + 1 rcp
    float e = __expf(-2.0f * fabsf(x));
    float t = (1.0f - e) * rcpf_(1.0f + e);
    return copysignf(t, x);
}

__global__ __launch_bounds__(256) void goal_kernel(
    const float* __restrict__ traj,
    const float* __restrict__ obsp,
    const float* __restrict__ h0,
    const float* __restrict__ c0,
    const float* __restrict__ noise,
    const float* __restrict__ encW,
    const float* __restrict__ encb,
    const float* __restrict__ Wih,
    const float* __restrict__ Whh,
    const float* __restrict__ bih,
    const float* __restrict__ bhh,
    const float* __restrict__ jW,
    const float* __restrict__ jb,
    const float* __restrict__ cW,
    const float* __restrict__ hW,
    const float* __restrict__ hb,
    const float* __restrict__ oW,
    const float* __restrict__ ob,
    float* __restrict__ out)
{
    const int b = blockIdx.x * blockDim.x + threadIdx.x;

    float h[16], c[16];
    {
        const float4* hp = reinterpret_cast<const float4*>(h0 + (size_t)b * 16);
        const float4* cp = reinterpret_cast<const float4*>(c0 + (size_t)b * 16);
        #pragma unroll
        for (int i = 0; i < 4; ++i) {
            float4 hv = hp[i], cv = cp[i];
            h[4*i+0]=hv.x; h[4*i+1]=hv.y; h[4*i+2]=hv.z; h[4*i+3]=hv.w;
            c[4*i+0]=cv.x; c[4*i+1]=cv.y; c[4*i+2]=cv.z; c[4*i+3]=cv.w;
        }
    }

    // ---- LSTM encoder: 8 steps, weights via uniform scalar loads ----
    for (int t = 0; t < OBS_N; ++t) {
        float2 xv = reinterpret_cast<const float2*>(traj + (size_t)t * B_N * 2)[b];
        float e[16];
        #pragma unroll
        for (int i = 0; i < 16; ++i)
            e[i] = fmaxf(fmaf(encW[2*i], xv.x, fmaf(encW[2*i+1], xv.y, encb[i])), 0.0f);
        float hn[16];
        #pragma unroll
        for (int j = 0; j < 16; ++j) {
            float gi = bih[j]    + bhh[j];
            float gf = bih[16+j] + bhh[16+j];
            float gg = bih[32+j] + bhh[32+j];
            float go = bih[48+j] + bhh[48+j];
            #pragma unroll
            for (int k = 0; k < 16; ++k) {
                gi = fmaf(Wih[j*16+k],      e[k], gi);
                gf = fmaf(Wih[(16+j)*16+k], e[k], gf);
                gg = fmaf(Wih[(32+j)*16+k], e[k], gg);
                go = fmaf(Wih[(48+j)*16+k], e[k], go);
                gi = fmaf(Whh[j*16+k],      h[k], gi);
                gf = fmaf(Whh[(16+j)*16+k], h[k], gf);
                gg = fmaf(Whh[(32+j)*16+k], h[k], gg);
                go = fmaf(Whh[(48+j)*16+k], h[k], go);
            }
            float cj = fmaf(sigm_(gf), c[j], sigm_(gi) * tanh_(gg));
            c[j] = cj;
            hn[j] = sigm_(go) * tanh_(cj);
        }
        #pragma unroll
        for (int j = 0; j < 16; ++j) h[j] = hn[j];
    }

    // ---- MAF sample (masks collapsed: i=0 iteration is constant-only) ----
    float2 nz = reinterpret_cast<const float2*>(noise)[b];
    float x0 = nz.x, x1 = nz.y;
    #pragma unroll
    for (int kf = NF_N - 1; kf >= 0; --kf) {
        float tswap = x0; x0 = x1; x1 = tswap;   // x = x[:, ::-1]
        const float* jWk = jW + kf*32;
        const float* jbk = jb + kf*16;
        const float* cWk = cW + kf*256;
        const float* hWk = hW + kf*256;
        const float* hbk = hb + kf*16;
        const float* oWk = oW + kf*64;
        const float* obk = ob + kf*4;

        // i = 0: m0 = ob[0], a0 = CLAMP*tanh(ob[2]/CLAMP)  (network-independent)
        float a0 = 5.0f * tanh_(obk[2] * 0.2f);
        x0 = fmaf(x0, __expf(a0), obk[0]);

        // i = 1: one MADE forward with x = [x0, 0] (joiner col 1 masked off)
        float h1[16];
        #pragma unroll
        for (int i = 0; i < 16; ++i) {
            float s = fmaf(jWk[2*i], x0, jbk[i]);
            #pragma unroll
            for (int k = 0; k < 16; ++k) s = fmaf(cWk[i*16+k], h[k], s);
            h1[i] = fmaxf(s, 0.0f);
        }
        float h2[16];
        #pragma unroll
        for (int i = 0; i < 16; ++i) {
            float s = hbk[i];
            #pragma unroll
            for (int k = 0; k < 16; ++k) s = fmaf(hWk[i*16+k], h1[k], s);
            h2[i] = fmaxf(s, 0.0f);
        }
        float m1 = obk[1], a1 = obk[3];
        #pragma unroll
        for (int k = 0; k < 16; ++k) {
            m1 = fmaf(oWk[16+k], h2[k], m1);   // output row 1
            a1 = fmaf(oWk[48+k], h2[k], a1);   // output row 3
        }
        a1 = 5.0f * tanh_(a1 * 0.2f);
        x1 = fmaf(x1, __expf(a1), m1);
    }

    float2 pp = reinterpret_cast<const float2*>(obsp + (size_t)(OBS_N-1) * B_N * 2)[b];
    float2 o; o.x = x0 + pp.x; o.y = x1 + pp.y;
    reinterpret_cast<float2*>(out)[b] = o;
}

extern "C" void kernel_launch(void* const* d_in, const int* in_sizes, int n_in,
                              void* d_out, int out_size, void* d_ws, size_t ws_size,
                              hipStream_t stream) {
    goal_kernel<<<B_N / 256, 256, 0, stream>>>(
        (const float*)d_in[0],  (const float*)d_in[1],  (const float*)d_in[2],
        (const float*)d_in[3],  (const float*)d_in[4],  (const float*)d_in[5],
        (const float*)d_in[6],  (const float*)d_in[7],  (const float*)d_in[8],
        (const float*)d_in[9],  (const float*)d_in[10], (const float*)d_in[11],
        (const float*)d_in[12], (const float*)d_in[13], (const float*)d_in[14],
        (const float*)d_in[15], (const float*)d_in[16], (const float*)d_in[17],
        (float*)d_out);
}

// Round 3
// 54.909 us; speedup vs baseline: 7.0048x; 7.0048x over previous
//
#include <hip/hip_runtime.h>

#define B_N 262144
#define OBS_N 8

typedef __attribute__((ext_vector_type(4))) _Float16 f16x4;
typedef __attribute__((ext_vector_type(2))) __fp16 fp16x2;
typedef __attribute__((ext_vector_type(4))) float f32x4;

#define LOG2E 1.44269504088896340736f

__device__ __forceinline__ float rcpf_(float x){ return __builtin_amdgcn_rcpf(x); }
__device__ __forceinline__ float exp2f_(float x){ return __builtin_amdgcn_exp2f(x); }
__device__ __forceinline__ float expf_(float x){ return exp2f_(LOG2E * x); }
// safe: x->+inf => 1, x->-inf => 0
__device__ __forceinline__ float sigm_(float x){ return rcpf_(1.0f + exp2f_(-LOG2E * x)); }
// safe: tanh(x) = 1 - 2/(exp2(2*log2e*x)+1); +inf->1, -inf->-1
__device__ __forceinline__ float tanh_(float x){ return fmaf(-2.0f, rcpf_(exp2f_((2.0f*LOG2E) * x) + 1.0f), 1.0f); }

__device__ __forceinline__ f16x4 pack4(float a, float b, float c, float d){
    fp16x2 lo = __builtin_amdgcn_cvt_pkrtz(a, b);
    fp16x2 hi = __builtin_amdgcn_cvt_pkrtz(c, d);
    f16x4 r;
    r[0] = (_Float16)lo[0]; r[1] = (_Float16)lo[1];
    r[2] = (_Float16)hi[0]; r[3] = (_Float16)hi[1];
    return r;
}

#define MFMA16(a, b, c) __builtin_amdgcn_mfma_f32_16x16x16f16((a), (b), (c), 0, 0, 0)

// Layout facts (v_mfma_f32_16x16x16_f16):
//   A: lane holds A[row = lane&15][k = 4*(lane>>4)+i]   (i = vector elem 0..3)
//   B: lane holds B[k = 4*(lane>>4)+i][col = lane&15]
//   C/D: lane holds C[row = 4*(lane>>4)+r][col = lane&15] (r = f32 elem 0..3)
// => D layout == next-GEMM B layout when batch = columns: recurrent h needs NO shuffle.

__global__ __launch_bounds__(256) void goal_kernel(
    const float* __restrict__ traj,
    const float* __restrict__ obsp,
    const float* __restrict__ h0,
    const float* __restrict__ c0,
    const float* __restrict__ noise,
    const float* __restrict__ encW,
    const float* __restrict__ encb,
    const float* __restrict__ Wih,
    const float* __restrict__ Whh,
    const float* __restrict__ bih,
    const float* __restrict__ bhh,
    const float* __restrict__ jW,
    const float* __restrict__ jb,
    const float* __restrict__ cW,
    const float* __restrict__ hW,
    const float* __restrict__ hb,
    const float* __restrict__ oW,
    const float* __restrict__ ob,
    float* __restrict__ out)
{
    const int lane = threadIdx.x & 63;
    const int wv   = threadIdx.x >> 6;
    const int q    = lane >> 4;        // k-block / row-block selector
    const int s    = lane & 15;        // column (batch) within tile / A-row
    const int j4   = q * 4;            // this lane's 4 hidden/k indices: j4+0..3
    const int base = blockIdx.x * 128 + wv * 32;   // 32 batch elems per wave
    const int colA = base + s;
    const int colB = base + 16 + s;

    // ---------------- preload (once) ----------------
    float ew0[4], ew1[4], eb[4];
    #pragma unroll
    for (int r = 0; r < 4; ++r) {
        ew0[r] = encW[(j4 + r) * 2 + 0];
        ew1[r] = encW[(j4 + r) * 2 + 1];
        eb[r]  = encb[j4 + r];
    }

    f16x4 wihA[4], whhA[4];
    f32x4 bias[4];
    #pragma unroll
    for (int m = 0; m < 4; ++m) {
        float4 wa = *(const float4*)(Wih + (16 * m + s) * 16 + j4);
        float4 wb = *(const float4*)(Whh + (16 * m + s) * 16 + j4);
        wihA[m] = pack4(wa.x, wa.y, wa.z, wa.w);
        whhA[m] = pack4(wb.x, wb.y, wb.z, wb.w);
        float4 b1 = *(const float4*)(bih + 16 * m + j4);
        float4 b2 = *(const float4*)(bhh + 16 * m + j4);
        f32x4 bv; bv[0] = b1.x + b2.x; bv[1] = b1.y + b2.y; bv[2] = b1.z + b2.z; bv[3] = b1.w + b2.w;
        bias[m] = bv;
    }

    // state: c in f32 (lane holds c[j4+r][col]), h as f16 B-fragment
    f32x4 cA = *(const f32x4*)(c0 + colA * 16 + j4);
    f32x4 cB = *(const f32x4*)(c0 + colB * 16 + j4);
    float4 hA0 = *(const float4*)(h0 + colA * 16 + j4);
    float4 hB0 = *(const float4*)(h0 + colB * 16 + j4);
    f16x4 hA = pack4(hA0.x, hA0.y, hA0.z, hA0.w);
    f16x4 hB = pack4(hB0.x, hB0.y, hB0.z, hB0.w);

    // noise early (hides latency under LSTM)
    float2 nzA = *(const float2*)(noise + colA * 2);
    float2 nzB = *(const float2*)(noise + colB * 2);

    // ---------------- LSTM encoder ----------------
    float2 xA = *(const float2*)(traj + colA * 2);
    float2 xB = *(const float2*)(traj + colB * 2);

    for (int t = 0; t < OBS_N; ++t) {
        float2 nxA, nxB;
        if (t < OBS_N - 1) {
            nxA = *(const float2*)(traj + (t + 1) * (B_N * 2) + colA * 2);
            nxB = *(const float2*)(traj + (t + 1) * (B_N * 2) + colB * 2);
        }
        // e = relu(encW x + encb), built directly in B-fragment layout
        float eAv[4], eBv[4];
        #pragma unroll
        for (int r = 0; r < 4; ++r) {
            eAv[r] = fmaxf(fmaf(ew0[r], xA.x, fmaf(ew1[r], xA.y, eb[r])), 0.0f);
            eBv[r] = fmaxf(fmaf(ew0[r], xB.x, fmaf(ew1[r], xB.y, eb[r])), 0.0f);
        }
        f16x4 eA = pack4(eAv[0], eAv[1], eAv[2], eAv[3]);
        f16x4 eB = pack4(eBv[0], eBv[1], eBv[2], eBv[3]);

        // gates[64][batch] = Wih@E + Whh@H + bias   (C-init = bias)
        f32x4 gA[4], gB[4];
        #pragma unroll
        for (int m = 0; m < 4; ++m) {
            gA[m] = MFMA16(wihA[m], eA, bias[m]);
            gA[m] = MFMA16(whhA[m], hA, gA[m]);
            gB[m] = MFMA16(wihA[m], eB, bias[m]);
            gB[m] = MFMA16(whhA[m], hB, gB[m]);
        }

        // per-lane LSTM cell update: lane holds (i,f,g,o) for j=j4+r, its 2 cols
        float hnA[4], hnB[4];
        #pragma unroll
        for (int r = 0; r < 4; ++r) {
            float cn = fmaf(sigm_(gA[1][r]), cA[r], sigm_(gA[0][r]) * tanh_(gA[2][r]));
            cA[r] = cn;
            hnA[r] = sigm_(gA[3][r]) * tanh_(cn);
            float cm = fmaf(sigm_(gB[1][r]), cB[r], sigm_(gB[0][r]) * tanh_(gB[2][r]));
            cB[r] = cm;
            hnB[r] = sigm_(gB[3][r]) * tanh_(cm);
        }
        hA = pack4(hnA[0], hnA[1], hnA[2], hnA[3]);   // == next-step B fragment
        hB = pack4(hnB[0], hnB[1], hnB[2], hnB[3]);

        if (t < OBS_N - 1) { xA = nxA; xB = nxB; }
    }

    // last obs position (issue loads before MAF compute)
    float2 ppA = *(const float2*)(obsp + (OBS_N - 1) * (B_N * 2) + colA * 2);
    float2 ppB = *(const float2*)(obsp + (OBS_N - 1) * (B_N * 2) + colB * 2);

    // ---------------- MAF sample ----------------
    float x0A = nzA.x, x1A = nzA.y;
    float x0B = nzB.x, x1B = nzB.y;

    #pragma unroll
    for (int kf = 3; kf >= 0; --kf) {
        // x = x[:, ::-1]
        float tA = x0A; x0A = x1A; x1A = tA;
        float tB = x0B; x0B = x1B; x1B = tB;

        // per-flow weights as A-fragments
        float4 cw = *(const float4*)(cW + kf * 256 + s * 16 + j4);
        f16x4 cwA = pack4(cw.x, cw.y, cw.z, cw.w);
        float4 hw = *(const float4*)(hW + kf * 256 + s * 16 + j4);
        f16x4 hwA = pack4(hw.x, hw.y, hw.z, hw.w);
        int orow = (s < 4) ? s : 0;
        float4 ow = *(const float4*)(oW + kf * 64 + orow * 16 + j4);
        f16x4 owA;
        if (s < 4) owA = pack4(ow.x, ow.y, ow.z, ow.w);
        else { owA[0] = (_Float16)0.f; owA[1] = (_Float16)0.f; owA[2] = (_Float16)0.f; owA[3] = (_Float16)0.f; }

        float jw0[4], jb_[4], hb_[4];
        #pragma unroll
        for (int r = 0; r < 4; ++r) {
            jw0[r] = jW[kf * 32 + (j4 + r) * 2];
            jb_[r] = jb[kf * 16 + j4 + r];
            hb_[r] = hb[kf * 16 + j4 + r];
        }
        float ob0 = ob[kf * 4 + 0], ob1 = ob[kf * 4 + 1];
        float ob2 = ob[kf * 4 + 2], ob3 = ob[kf * 4 + 3];

        // i=0: output rows 0,2 fully masked -> constants
        float ea0 = expf_(5.0f * tanh_(ob2 * 0.2f));
        x0A = fmaf(x0A, ea0, ob0);
        x0B = fmaf(x0B, ea0, ob0);

        // i=1: h1 = relu(jW[:,0]*x0 + jb + cW@h)
        f32x4 a1A, a1B;
        #pragma unroll
        for (int r = 0; r < 4; ++r) {
            a1A[r] = fmaf(jw0[r], x0A, jb_[r]);
            a1B[r] = fmaf(jw0[r], x0B, jb_[r]);
        }
        a1A = MFMA16(cwA, hA, a1A);
        a1B = MFMA16(cwA, hB, a1B);
        f16x4 h1A = pack4(fmaxf(a1A[0],0.f), fmaxf(a1A[1],0.f), fmaxf(a1A[2],0.f), fmaxf(a1A[3],0.f));
        f16x4 h1B = pack4(fmaxf(a1B[0],0.f), fmaxf(a1B[1],0.f), fmaxf(a1B[2],0.f), fmaxf(a1B[3],0.f));

        // h2 = relu(hW@h1 + hb)
        f32x4 a2A, a2B;
        #pragma unroll
        for (int r = 0; r < 4; ++r) { a2A[r] = hb_[r]; a2B[r] = hb_[r]; }
        a2A = MFMA16(hwA, h1A, a2A);
        a2B = MFMA16(hwA, h1B, a2B);
        f16x4 h2A = pack4(fmaxf(a2A[0],0.f), fmaxf(a2A[1],0.f), fmaxf(a2A[2],0.f), fmaxf(a2A[3],0.f));
        f16x4 h2B = pack4(fmaxf(a2B[0],0.f), fmaxf(a2B[1],0.f), fmaxf(a2B[2],0.f), fmaxf(a2B[3],0.f));

        // out = oW@h2 + ob: rows 1 (m1) and 3 (a1) land in lanes q==0
        f32x4 a3A, a3B;
        if (q == 0) { a3A[0]=ob0; a3A[1]=ob1; a3A[2]=ob2; a3A[3]=ob3;
                      a3B[0]=ob0; a3B[1]=ob1; a3B[2]=ob2; a3B[3]=ob3; }
        else        { a3A[0]=0.f; a3A[1]=0.f; a3A[2]=0.f; a3A[3]=0.f;
                      a3B[0]=0.f; a3B[1]=0.f; a3B[2]=0.f; a3B[3]=0.f; }
        a3A = MFMA16(owA, h2A, a3A);
        a3B = MFMA16(owA, h2B, a3B);

        float a1vA = 5.0f * tanh_(a3A[3] * 0.2f);
        float a1vB = 5.0f * tanh_(a3B[3] * 0.2f);
        float x1nA = fmaf(x1A, expf_(a1vA), a3A[1]);
        float x1nB = fmaf(x1B, expf_(a1vB), a3B[1]);
        // broadcast valid result (lanes 0..15) to all lanes of same column
        x1A = __int_as_float(__builtin_amdgcn_ds_bpermute(s << 2, __float_as_int(x1nA)));
        x1B = __int_as_float(__builtin_amdgcn_ds_bpermute(s << 2, __float_as_int(x1nB)));
    }

    if (lane < 16) {
        float2 oA; oA.x = x0A + ppA.x; oA.y = x1A + ppA.y;
        float2 oB; oB.x = x0B + ppB.x; oB.y = x1B + ppB.y;
        *(float2*)(out + colA * 2) = oA;
        *(float2*)(out + colB * 2) = oB;
    }
}

extern "C" void kernel_launch(void* const* d_in, const int* in_sizes, int n_in,
                              void* d_out, int out_size, void* d_ws, size_t ws_size,
                              hipStream_t stream) {
    goal_kernel<<<B_N / 128, 256, 0, stream>>>(
        (const float*)d_in[0],  (const float*)d_in[1],  (const float*)d_in[2],
        (const float*)d_in[3],  (const float*)d_in[4],  (const float*)d_in[5],
        (const float*)d_in[6],  (const float*)d_in[7],  (const float*)d_in[8],
        (const float*)d_in[9],  (const float*)d_in[10], (const float*)d_in[11],
        (const float*)d_in[12], (const float*)d_in[13], (const float*)d_in[14],
        (const float*)d_in[15], (const float*)d_in[16], (const float*)d_in[17],
        (float*)d_out);
}

// Round 4
// 50.222 us; speedup vs baseline: 7.6585x; 1.0933x over previous
//
#include <hip/hip_runtime.h>

#define B_N 262144
#define OBS_N 8

typedef __attribute__((ext_vector_type(4))) _Float16 f16x4;
typedef __attribute__((ext_vector_type(2))) __fp16 fp16x2;
typedef __attribute__((ext_vector_type(4))) float f32x4;

#define LOG2E 1.44269504088896340736f

__device__ __forceinline__ float rcpf_(float x){ return __builtin_amdgcn_rcpf(x); }
__device__ __forceinline__ float exp2f_(float x){ return __builtin_amdgcn_exp2f(x); }
__device__ __forceinline__ float expf_(float x){ return exp2f_(LOG2E * x); }
// exact for all signs: tanh(x) = 1 - 2/(exp2(2*log2e*x)+1)
__device__ __forceinline__ float tanh_(float x){ return fmaf(-2.0f, rcpf_(exp2f_((2.0f*LOG2E) * x) + 1.0f), 1.0f); }

__device__ __forceinline__ f16x4 pack4(float a, float b, float c, float d){
    fp16x2 lo = __builtin_amdgcn_cvt_pkrtz(a, b);
    fp16x2 hi = __builtin_amdgcn_cvt_pkrtz(c, d);
    f16x4 r;
    r[0] = (_Float16)lo[0]; r[1] = (_Float16)lo[1];
    r[2] = (_Float16)hi[0]; r[3] = (_Float16)hi[1];
    return r;
}

#define MFMA16(a, b, c) __builtin_amdgcn_mfma_f32_16x16x16f16((a), (b), (c), 0, 0, 0)

// Layout facts (v_mfma_f32_16x16x16_f16):
//   A: lane holds A[row = lane&15][k = 4*(lane>>4)+i]
//   B: lane holds B[k = 4*(lane>>4)+i][col = lane&15]
//   C/D: lane holds C[row = 4*(lane>>4)+r][col = lane&15]
// => D layout == next-GEMM B layout (batch in columns): recurrence needs no shuffle.

__global__ __launch_bounds__(256) void goal_kernel(
    const float* __restrict__ traj,
    const float* __restrict__ obsp,
    const float* __restrict__ h0,
    const float* __restrict__ c0,
    const float* __restrict__ noise,
    const float* __restrict__ encW,
    const float* __restrict__ encb,
    const float* __restrict__ Wih,
    const float* __restrict__ Whh,
    const float* __restrict__ bih,
    const float* __restrict__ bhh,
    const float* __restrict__ jW,
    const float* __restrict__ jb,
    const float* __restrict__ cW,
    const float* __restrict__ hW,
    const float* __restrict__ hb,
    const float* __restrict__ oW,
    const float* __restrict__ ob,
    float* __restrict__ out)
{
    const int lane = threadIdx.x & 63;
    const int wv   = threadIdx.x >> 6;
    const int q    = lane >> 4;
    const int s    = lane & 15;
    const int j4   = q * 4;
    const int base = blockIdx.x * 128 + wv * 32;
    const int colA = base + s;
    const int colB = base + 16 + s;

    // ---------------- preload (once) ----------------
    float ew0[4], ew1[4], eb[4];
    #pragma unroll
    for (int r = 0; r < 4; ++r) {
        ew0[r] = encW[(j4 + r) * 2 + 0];
        ew1[r] = encW[(j4 + r) * 2 + 1];
        eb[r]  = encb[j4 + r];
    }

    // gate exp2-arg pre-scaling folded into weights+bias:
    //   i,f,o rows: * -log2e   (E = 2^{g~} = e^{-g})
    //   g row:      * -2log2e  (E = e^{-2g})
    const float gsc[4] = { -LOG2E, -LOG2E, -2.0f*LOG2E, -LOG2E };

    f16x4 wihA[4], whhA[4];
    f32x4 bias[4];
    #pragma unroll
    for (int m = 0; m < 4; ++m) {
        float4 wa = *(const float4*)(Wih + (16 * m + s) * 16 + j4);
        float4 wb = *(const float4*)(Whh + (16 * m + s) * 16 + j4);
        wihA[m] = pack4(wa.x*gsc[m], wa.y*gsc[m], wa.z*gsc[m], wa.w*gsc[m]);
        whhA[m] = pack4(wb.x*gsc[m], wb.y*gsc[m], wb.z*gsc[m], wb.w*gsc[m]);
        float4 b1 = *(const float4*)(bih + 16 * m + j4);
        float4 b2 = *(const float4*)(bhh + 16 * m + j4);
        f32x4 bv;
        bv[0] = (b1.x + b2.x)*gsc[m]; bv[1] = (b1.y + b2.y)*gsc[m];
        bv[2] = (b1.z + b2.z)*gsc[m]; bv[3] = (b1.w + b2.w)*gsc[m];
        bias[m] = bv;
    }

    // per-flow constants hoisted (ob-derived, data-independent)
    float ob0c[4], ob1c[4], ob2c[4], ob3c[4], ea0c[4];
    #pragma unroll
    for (int kf = 0; kf < 4; ++kf) {
        ob0c[kf] = ob[kf*4 + 0];
        ob1c[kf] = ob[kf*4 + 1];
        ob2c[kf] = ob[kf*4 + 2];
        ob3c[kf] = ob[kf*4 + 3] * 0.2f;                      // 1/CLAMP folded
        ea0c[kf] = expf_(5.0f * tanh_(ob2c[kf] * 0.2f));     // e^{a0}, flow const
    }

    // state
    f32x4 cA = *(const f32x4*)(c0 + colA * 16 + j4);
    f32x4 cB = *(const f32x4*)(c0 + colB * 16 + j4);
    float4 hA0 = *(const float4*)(h0 + colA * 16 + j4);
    float4 hB0 = *(const float4*)(h0 + colB * 16 + j4);
    f16x4 hA = pack4(hA0.x, hA0.y, hA0.z, hA0.w);
    f16x4 hB = pack4(hB0.x, hB0.y, hB0.z, hB0.w);

    float2 nzA = *(const float2*)(noise + colA * 2);
    float2 nzB = *(const float2*)(noise + colB * 2);

    // ---------------- LSTM encoder ----------------
    float2 xA = *(const float2*)(traj + colA * 2);
    float2 xB = *(const float2*)(traj + colB * 2);

    const float NEG2L2E = -2.0f * LOG2E;

    for (int t = 0; t < OBS_N; ++t) {
        float2 nxA, nxB;
        if (t < OBS_N - 1) {
            nxA = *(const float2*)(traj + (t + 1) * (B_N * 2) + colA * 2);
            nxB = *(const float2*)(traj + (t + 1) * (B_N * 2) + colB * 2);
        }
        float eAv[4], eBv[4];
        #pragma unroll
        for (int r = 0; r < 4; ++r) {
            eAv[r] = fmaxf(fmaf(ew0[r], xA.x, fmaf(ew1[r], xA.y, eb[r])), 0.0f);
            eBv[r] = fmaxf(fmaf(ew0[r], xB.x, fmaf(ew1[r], xB.y, eb[r])), 0.0f);
        }
        f16x4 eA = pack4(eAv[0], eAv[1], eAv[2], eAv[3]);
        f16x4 eB = pack4(eBv[0], eBv[1], eBv[2], eBv[3]);

        f32x4 gA[4], gB[4];
        #pragma unroll
        for (int m = 0; m < 4; ++m) {
            gA[m] = MFMA16(wihA[m], eA, bias[m]);
            gA[m] = MFMA16(whhA[m], hA, gA[m]);
            gB[m] = MFMA16(wihA[m], eB, bias[m]);
            gB[m] = MFMA16(whhA[m], hB, gB[m]);
        }

        // cell update: gates are pre-scaled exp2 args.
        // c' = [c*(1+Ei)(1+Eg) + (1-Eg)(1+Ef)] / ((1+Ei)(1+Eg)(1+Ef))
        // h  = (1-Ec) / ((1+Ec)(1+Eo)),  Ec = 2^(-2log2e*c')
        float hnA[4], hnB[4];
        #pragma unroll
        for (int r = 0; r < 4; ++r) {
            {
                float Ei = exp2f_(gA[0][r]);
                float Ef = exp2f_(gA[1][r]);
                float Eg = exp2f_(gA[2][r]);
                float Eo = exp2f_(gA[3][r]);
                float pi = 1.0f + Ei, pf = 1.0f + Ef, pg = 1.0f + Eg;
                float m_ = pi * pg;
                float R1 = rcpf_(m_ * pf);
                float cn = fmaf(cA[r], m_, (1.0f - Eg) * pf) * R1;
                cA[r] = cn;
                float Ec = exp2f_(NEG2L2E * cn);
                float R2 = rcpf_((1.0f + Ec) * (1.0f + Eo));
                hnA[r] = (1.0f - Ec) * R2;
            }
            {
                float Ei = exp2f_(gB[0][r]);
                float Ef = exp2f_(gB[1][r]);
                float Eg = exp2f_(gB[2][r]);
                float Eo = exp2f_(gB[3][r]);
                float pi = 1.0f + Ei, pf = 1.0f + Ef, pg = 1.0f + Eg;
                float m_ = pi * pg;
                float R1 = rcpf_(m_ * pf);
                float cn = fmaf(cB[r], m_, (1.0f - Eg) * pf) * R1;
                cB[r] = cn;
                float Ec = exp2f_(NEG2L2E * cn);
                float R2 = rcpf_((1.0f + Ec) * (1.0f + Eo));
                hnB[r] = (1.0f - Ec) * R2;
            }
        }
        hA = pack4(hnA[0], hnA[1], hnA[2], hnA[3]);
        hB = pack4(hnB[0], hnB[1], hnB[2], hnB[3]);

        if (t < OBS_N - 1) { xA = nxA; xB = nxB; }
    }

    float2 ppA = *(const float2*)(obsp + (OBS_N - 1) * (B_N * 2) + colA * 2);
    float2 ppB = *(const float2*)(obsp + (OBS_N - 1) * (B_N * 2) + colB * 2);

    // ---------------- MAF sample ----------------
    float x0A = nzA.x, x1A = nzA.y;
    float x0B = nzB.x, x1B = nzB.y;

    #pragma unroll
    for (int kf = 3; kf >= 0; --kf) {
        float tA = x0A; x0A = x1A; x1A = tA;
        float tB = x0B; x0B = x1B; x1B = tB;

        float4 cw = *(const float4*)(cW + kf * 256 + s * 16 + j4);
        f16x4 cwA = pack4(cw.x, cw.y, cw.z, cw.w);
        float4 hw = *(const float4*)(hW + kf * 256 + s * 16 + j4);
        f16x4 hwA = pack4(hw.x, hw.y, hw.z, hw.w);
        // oW rows replicated with period 4 => every lane group q computes
        // output rows 0..3; row 3 pre-scaled by 1/CLAMP.
        {
        }
        float osc = ((s & 3) == 3) ? 0.2f : 1.0f;
        float4 ow = *(const float4*)(oW + kf * 64 + (s & 3) * 16 + j4);
        f16x4 owA = pack4(ow.x * osc, ow.y * osc, ow.z * osc, ow.w * osc);

        float jw0[4], jb_[4], hb_[4];
        #pragma unroll
        for (int r = 0; r < 4; ++r) {
            jw0[r] = jW[kf * 32 + (j4 + r) * 2];
            jb_[r] = jb[kf * 16 + j4 + r];
            hb_[r] = hb[kf * 16 + j4 + r];
        }

        // i=0 (constants, hoisted)
        x0A = fmaf(x0A, ea0c[kf], ob0c[kf]);
        x0B = fmaf(x0B, ea0c[kf], ob0c[kf]);

        // i=1: h1 = relu(jW0*x0 + jb + cW@h)
        f32x4 a1A, a1B;
        #pragma unroll
        for (int r = 0; r < 4; ++r) {
            a1A[r] = fmaf(jw0[r], x0A, jb_[r]);
            a1B[r] = fmaf(jw0[r], x0B, jb_[r]);
        }
        a1A = MFMA16(cwA, hA, a1A);
        a1B = MFMA16(cwA, hB, a1B);
        f16x4 h1A = pack4(fmaxf(a1A[0],0.f), fmaxf(a1A[1],0.f), fmaxf(a1A[2],0.f), fmaxf(a1A[3],0.f));
        f16x4 h1B = pack4(fmaxf(a1B[0],0.f), fmaxf(a1B[1],0.f), fmaxf(a1B[2],0.f), fmaxf(a1B[3],0.f));

        f32x4 a2A, a2B;
        #pragma unroll
        for (int r = 0; r < 4; ++r) { a2A[r] = hb_[r]; a2B[r] = hb_[r]; }
        a2A = MFMA16(hwA, h1A, a2A);
        a2B = MFMA16(hwA, h1B, a2B);
        f16x4 h2A = pack4(fmaxf(a2A[0],0.f), fmaxf(a2A[1],0.f), fmaxf(a2A[2],0.f), fmaxf(a2A[3],0.f));
        f16x4 h2B = pack4(fmaxf(a2B[0],0.f), fmaxf(a2B[1],0.f), fmaxf(a2B[2],0.f), fmaxf(a2B[3],0.f));

        // out rows replicated: acc[r] = out-row r for EVERY lane (no bpermute)
        f32x4 a3A, a3B;
        a3A[0]=ob0c[kf]; a3A[1]=ob1c[kf]; a3A[2]=ob2c[kf]; a3A[3]=ob3c[kf];
        a3B[0]=ob0c[kf]; a3B[1]=ob1c[kf]; a3B[2]=ob2c[kf]; a3B[3]=ob3c[kf];
        a3A = MFMA16(owA, h2A, a3A);
        a3B = MFMA16(owA, h2B, a3B);

        float a1vA = 5.0f * tanh_(a3A[3]);   // 0.2 already folded into row 3
        float a1vB = 5.0f * tanh_(a3B[3]);
        x1A = fmaf(x1A, expf_(a1vA), a3A[1]);
        x1B = fmaf(x1B, expf_(a1vB), a3B[1]);
    }

    if (q == 0) {
        float2 oA; oA.x = x0A + ppA.x; oA.y = x1A + ppA.y;
        float2 oB; oB.x = x0B + ppB.x; oB.y = x1B + ppB.y;
        *(float2*)(out + colA * 2) = oA;
        *(float2*)(out + colB * 2) = oB;
    }
}

extern "C" void kernel_launch(void* const* d_in, const int* in_sizes, int n_in,
                              void* d_out, int out_size, void* d_ws, size_t ws_size,
                              hipStream_t stream) {
    goal_kernel<<<B_N / 128, 256, 0, stream>>>(
        (const float*)d_in[0],  (const float*)d_in[1],  (const float*)d_in[2],
        (const float*)d_in[3],  (const float*)d_in[4],  (const float*)d_in[5],
        (const float*)d_in[6],  (const float*)d_in[7],  (const float*)d_in[8],
        (const float*)d_in[9],  (const float*)d_in[10], (const float*)d_in[11],
        (const float*)d_in[12], (const float*)d_in[13], (const float*)d_in[14],
        (const float*)d_in[15], (const float*)d_in[16], (const float*)d_in[17],
        (float*)d_out);
}